// Round 7
// baseline (102.487 us; speedup 1.0000x reference)
//
#include <hip/hip_runtime.h>
#include <math.h>

#define NATOMS    128
#define NSEG      7875     // segments: i in [0,124], j in [i+2,126]
#define NSEG_PAD  8192     // padded so Phase A needs no predication
#define NPAIR     8128     // pairs (a,b), 0 <= a < b <= 127
#define OUT_PER_B 16256    // 128*127 (row-major, diagonal skipped)
#define BLOCK     512

typedef float v2f __attribute__((ext_vector_type(2)));
__device__ __forceinline__ v2f mk2(float a, float b) { v2f r; r.x = a; r.y = b; return r; }

struct P3 { v2f x, y, z; };
__device__ __forceinline__ P3 psub(P3 a, P3 b) { return {a.x - b.x, a.y - b.y, a.z - b.z}; }
__device__ __forceinline__ P3 pcross(P3 a, P3 b) {
    return {a.y * b.z - a.z * b.y, a.z * b.x - a.x * b.z, a.x * b.y - a.y * b.x};
}
__device__ __forceinline__ v2f pdot(P3 a, P3 b) { return a.x * b.x + a.y * b.y + a.z * b.z; }
__device__ __forceinline__ v2f prsq(v2f q) {
    v2f r; r.x = __builtin_amdgcn_rsqf(q.x); r.y = __builtin_amdgcn_rsqf(q.y); return r;
}
__device__ __forceinline__ v2f pclip1(v2f x) {
    return __builtin_elementwise_min(__builtin_elementwise_max(x, mk2(-1.f, -1.f)),
                                     mk2(1.f, 1.f));
}

// Packed 4-term branchless asin, A&S 4.4.45 (|err| <= 6.8e-5).
__device__ __forceinline__ v2f fast_asin2(v2f x) {
    v2f a = __builtin_elementwise_abs(x);
    v2f p = mk2(-0.0187293f, -0.0187293f);
    p = p * a + mk2( 0.0742610f,  0.0742610f);
    p = p * a + mk2(-0.2121144f, -0.2121144f);
    p = p * a + mk2( 1.5707288f,  1.5707288f);
    v2f om = mk2(1.0f, 1.0f) - a;
    v2f sq; sq.x = __builtin_amdgcn_sqrtf(om.x); sq.y = __builtin_amdgcn_sqrtf(om.y);
    v2f r = mk2(1.57079632679f, 1.57079632679f) - sq * p;
    return __builtin_elementwise_copysign(r, x);
}

__device__ __forceinline__ int seg_row_base(int i) { return 125 * i - (__umul24(i, i - 1) >> 1); }

__device__ __forceinline__ P3 pack3(const float4 &a, const float4 &b) {
    return { mk2(a.x, b.x), mk2(a.y, b.y), mk2(a.z, b.z) };
}

// Writhe for TWO packed segments (x-lane = pa, y-lane = pb). Coordinates from
// float4 LDS (1 ds_read_b128 per point per sub-lane). Sign via the exact
// identity  cross(p3-p2, p1-p0) . u0 = -(u3 x u2) . u0 = -n2 . u0.
__device__ __forceinline__ v2f seg_writhe_pair(unsigned pa, unsigned pb,
                                               const float4* sp4) {
    int jA = (int)(pa & 127u), iA = (int)(pa >> 7);
    int jB = (int)(pb & 127u), iB = (int)(pb >> 7);

    float4 A0 = sp4[iA], A1 = sp4[iA + 1], A2 = sp4[jA], A3 = sp4[jA + 1];
    float4 B0 = sp4[iB], B1 = sp4[iB + 1], B2 = sp4[jB], B3 = sp4[jB + 1];

    P3 p0 = pack3(A0, B0);
    P3 p1 = pack3(A1, B1);
    P3 p2 = pack3(A2, B2);
    P3 p3 = pack3(A3, B3);

    P3 u0 = psub(p2, p0);
    P3 u1 = psub(p3, p0);
    P3 u2 = psub(p2, p1);
    P3 u3 = psub(p3, p1);

    P3 n0 = pcross(u0, u1);
    P3 n1 = pcross(u1, u3);
    P3 n2 = pcross(u3, u2);
    P3 n3 = pcross(u2, u0);

    v2f q0 = pdot(n0, n0);
    v2f q1 = pdot(n1, n1);
    v2f q2 = pdot(n2, n2);
    v2f q3 = pdot(n3, n3);

    v2f c0 = pclip1(pdot(n0, n1) * prsq(q0 * q1));
    v2f c1 = pclip1(pdot(n1, n2) * prsq(q1 * q2));
    v2f c2 = pclip1(pdot(n2, n3) * prsq(q2 * q3));
    v2f c3 = pclip1(pdot(n3, n0) * prsq(q3 * q0));

    v2f sd = pdot(n2, u0);     // = -(reference sd); sign folded below
    v2f omega = fast_asin2(c0) + fast_asin2(c1) + fast_asin2(c2) + fast_asin2(c3);

    v2f sgn;
    sgn.x = (sd.x > 0.f) ? -1.f : ((sd.x < 0.f) ? 1.f : 0.f);
    sgn.y = (sd.y > 0.f) ? -1.f : ((sd.y < 0.f) ? 1.f : 0.f);

    return omega * sgn * mk2(0.15915494309189535f, 0.15915494309189535f);
}

// INSTRUMENTATION ROUND (intentionally not the final config):
// Phase A executes TWICE (idempotent: rep 1 rewrites identical swr values;
// barrier between reps prevents elimination; output unchanged).
// Purpose: (1) dur_new - 92us = marginal Phase A wall time; (2) kernel
// duration exceeds the ~44us poison-fill dispatches so the kernel's OWN
// rocprof counter row (VALUBusy / LDS conflicts / FETCH / WRITE / occupancy)
// becomes visible for the first time in this session.
// Calibration so far: dur_us = ~54us fixed harness (fill 44 + overhead 10)
// + kernel (~38us, invariant across 4 structurally different variants --
// which no throughput model explains; hence this measurement).
__global__ __launch_bounds__(BLOCK, 2) void writhe_fused(
    const float* __restrict__ xyz,       // (B, 128, 3)
    float*       __restrict__ out)       // (B, 16256)
{
    __shared__ float4 sp4[NATOMS];
    __shared__ float  swr[NSEG_PAD];
    __shared__ unsigned short sidx[NSEG_PAD];

    const int b = blockIdx.x;
    const int t = threadIdx.x;

    if (t < 3 * NATOMS) {
        float v = xyz[(size_t)b * (3 * NATOMS) + t];
        int a = t / 3, c = t - 3 * a;
        ((float*)&sp4[a])[c] = v;
    }

    // ---------- Phase 0: build sidx (+ pad tail with a safe segment) ----------
    {
        int s = t * 16;
        if (s < NSEG) {
            int i = (int)((251.0f - __builtin_amdgcn_sqrtf(63001.0f - 8.0f * (float)s)) * 0.5f);
            i = max(i, 0);
            i += (seg_row_base(i + 1) <= s);
            i += (seg_row_base(i + 1) <= s);
            i -= (seg_row_base(i) > s);
            i -= (seg_row_base(i) > s);
            int j = s - seg_row_base(i) + i + 2;
            #pragma unroll
            for (int k = 0; k < 16; ++k) {
                if (s < NSEG) sidx[s] = (unsigned short)((i << 7) | j);
                ++s; ++j;
                if (j > 126) { ++i; j = i + 2; }
            }
        }
        if (t < NSEG_PAD - NSEG) sidx[NSEG + t] = (unsigned short)((124 << 7) | 126);
    }
    __syncthreads();

    // ---------- Phase A x2 (instrumented): packed-pair writhe ----------
    #pragma unroll 1
    for (int rep = 0; rep < 2; ++rep) {
        #pragma unroll
        for (int g = 0; g < 4; ++g) {
            const int sA = g * 2048 + t;     // sA..sA+1536 < 8192: unconditional
            v2f w1 = seg_writhe_pair(sidx[sA],        sidx[sA + 512],  sp4);
            v2f w2 = seg_writhe_pair(sidx[sA + 1024], sidx[sA + 1536], sp4);
            swr[sA]        = w1.x;
            swr[sA + 512]  = w1.y;
            swr[sA + 1024] = w2.x;
            swr[sA + 1536] = w2.y;
        }
        __syncthreads();   // rep boundary: orders LDS writes, prevents elision
    }

    // ---------- Phase D: lane-consecutive gather + coalesced store ----------
    // k in [0, 16256): r = k/127 (exact magic mul), c' = k%127, c = c' + (c'>=r).
    float* ob = out + (size_t)b * OUT_PER_B;
    for (int k = t; k < OUT_PER_B; k += BLOCK) {
        const int r = (int)(((unsigned)k * 132105u) >> 24);
        int c = k - r * 127;
        c += (c >= r);
        const int a  = min(r, c);
        const int bb = max(r, c);

        // segment ids for (i,j) in {a-1,a} x {b-1,b}; s(i,j)=base(i)+j-i-2
        const int am1 = a - 1;
        const int s00 = 125 * am1 - ((am1 * (am1 - 1)) >> 1) + bb - a - 2;  // (a-1, b-1)
        const int s10 = s00 + 125 - a;                                      // (a,   b-1)

        const bool v00 = (a >= 1) && (a <= 125) && (bb >= a + 2);
        const bool v01 = (a >= 1) && (a <= 125) && (bb <= 126);
        const bool v10 = (a <= 124) && (bb >= a + 3);
        const bool v11 = (a <= 124) && (bb <= 126) && (bb >= a + 2);

        const int c00 = min(max(s00,     0), NSEG - 1);
        const int c01 = min(max(s00 + 1, 0), NSEG - 1);
        const int c10 = min(max(s10,     0), NSEG - 1);
        const int c11 = min(max(s10 + 1, 0), NSEG - 1);

        float sum = (v00 ? swr[c00] : 0.0f) + (v01 ? swr[c01] : 0.0f)
                  + (v10 ? swr[c10] : 0.0f) + (v11 ? swr[c11] : 0.0f);

        __builtin_nontemporal_store(sum, ob + k);
    }
}

extern "C" void kernel_launch(void* const* d_in, const int* in_sizes, int n_in,
                              void* d_out, int out_size, void* d_ws, size_t ws_size,
                              hipStream_t stream) {
    const float* xyz = (const float*)d_in[0];
    float*       out = (float*)d_out;

    int B = in_sizes[0] / (NATOMS * 3);   // 512 for the reference shapes
    writhe_fused<<<B, BLOCK, 0, stream>>>(xyz, out);
}

// Round 8
// 88.187 us; speedup vs baseline: 1.1622x; 1.1622x over previous
//
#include <hip/hip_runtime.h>
#include <math.h>

#define NATOMS    128
#define NSEG      7875     // segments: i in [0,124], j in [i+2,126]
#define NSEG_PAD  8192     // padded so Phase A needs no predication
#define OUT_PER_B 16256    // 128*127 (row-major, diagonal skipped)
#define BLOCK     512
#define TBLOCK    512
#define SIDX_BYTES 16384                        // u16[8192]
#define WS_NEED   (SIDX_BYTES + OUT_PER_B * 8)  // + uint2[16256] = 146,432 B
#define ZSLOT_OFF (NSEG_PAD * 4)                // byte offset of swr zero slot

typedef float v2f __attribute__((ext_vector_type(2)));
__device__ __forceinline__ v2f mk2(float a, float b) { v2f r; r.x = a; r.y = b; return r; }

struct P3 { v2f x, y, z; };
__device__ __forceinline__ P3 psub(P3 a, P3 b) { return {a.x - b.x, a.y - b.y, a.z - b.z}; }
__device__ __forceinline__ P3 pcross(P3 a, P3 b) {
    return {a.y * b.z - a.z * b.y, a.z * b.x - a.x * b.z, a.x * b.y - a.y * b.x};
}
__device__ __forceinline__ v2f pdot(P3 a, P3 b) { return a.x * b.x + a.y * b.y + a.z * b.z; }
__device__ __forceinline__ v2f prsq(v2f q) {
    v2f r; r.x = __builtin_amdgcn_rsqf(q.x); r.y = __builtin_amdgcn_rsqf(q.y); return r;
}
__device__ __forceinline__ v2f pclip1(v2f x) {
    return __builtin_elementwise_min(__builtin_elementwise_max(x, mk2(-1.f, -1.f)),
                                     mk2(1.f, 1.f));
}

// Packed 4-term branchless asin, A&S 4.4.45 (|err| <= 6.8e-5).
__device__ __forceinline__ v2f fast_asin2(v2f x) {
    v2f a = __builtin_elementwise_abs(x);
    v2f p = mk2(-0.0187293f, -0.0187293f);
    p = p * a + mk2( 0.0742610f,  0.0742610f);
    p = p * a + mk2(-0.2121144f, -0.2121144f);
    p = p * a + mk2( 1.5707288f,  1.5707288f);
    v2f om = mk2(1.0f, 1.0f) - a;
    v2f sq; sq.x = __builtin_amdgcn_sqrtf(om.x); sq.y = __builtin_amdgcn_sqrtf(om.y);
    v2f r = mk2(1.57079632679f, 1.57079632679f) - sq * p;
    return __builtin_elementwise_copysign(r, x);
}

__device__ __forceinline__ int seg_row_base(int i) { return 125 * i - (__umul24(i, i - 1) >> 1); }

// (i,j) from linear segment id s (sqrt seed + exact fixup); s must be < NSEG.
__device__ __forceinline__ void seed_ij(int s, int &i, int &j) {
    i = (int)((251.0f - __builtin_amdgcn_sqrtf(63001.0f - 8.0f * (float)s)) * 0.5f);
    i = max(i, 0);
    i += (seg_row_base(i + 1) <= s);
    i += (seg_row_base(i + 1) <= s);
    i -= (seg_row_base(i) > s);
    i -= (seg_row_base(i) > s);
    j = s - seg_row_base(i) + i + 2;
}

__device__ __forceinline__ P3 pack3(const float4 &a, const float4 &b) {
    return { mk2(a.x, b.x), mk2(a.y, b.y), mk2(a.z, b.z) };
}

// Writhe for TWO packed segments (x-lane = pa, y-lane = pb). Coordinates from
// float4 LDS. Sign via the exact identity
//   cross(p3-p2, p1-p0) . u0 = -(u3 x u2) . u0 = -n2 . u0.
__device__ __forceinline__ v2f seg_writhe_pair(unsigned pa, unsigned pb,
                                               const float4* sp4) {
    int jA = (int)(pa & 127u), iA = (int)(pa >> 7);
    int jB = (int)(pb & 127u), iB = (int)(pb >> 7);

    float4 A0 = sp4[iA], A1 = sp4[iA + 1], A2 = sp4[jA], A3 = sp4[jA + 1];
    float4 B0 = sp4[iB], B1 = sp4[iB + 1], B2 = sp4[jB], B3 = sp4[jB + 1];

    P3 p0 = pack3(A0, B0);
    P3 p1 = pack3(A1, B1);
    P3 p2 = pack3(A2, B2);
    P3 p3 = pack3(A3, B3);

    P3 u0 = psub(p2, p0);
    P3 u1 = psub(p3, p0);
    P3 u2 = psub(p2, p1);
    P3 u3 = psub(p3, p1);

    P3 n0 = pcross(u0, u1);
    P3 n1 = pcross(u1, u3);
    P3 n2 = pcross(u3, u2);
    P3 n3 = pcross(u2, u0);

    v2f q0 = pdot(n0, n0);
    v2f q1 = pdot(n1, n1);
    v2f q2 = pdot(n2, n2);
    v2f q3 = pdot(n3, n3);

    v2f c0 = pclip1(pdot(n0, n1) * prsq(q0 * q1));
    v2f c1 = pclip1(pdot(n1, n2) * prsq(q1 * q2));
    v2f c2 = pclip1(pdot(n2, n3) * prsq(q2 * q3));
    v2f c3 = pclip1(pdot(n3, n0) * prsq(q3 * q0));

    v2f sd = pdot(n2, u0);     // = -(reference sd); sign folded below
    v2f omega = fast_asin2(c0) + fast_asin2(c1) + fast_asin2(c2) + fast_asin2(c3);

    v2f sgn;
    sgn.x = (sd.x > 0.f) ? -1.f : ((sd.x < 0.f) ? 1.f : 0.f);
    sgn.y = (sd.y > 0.f) ? -1.f : ((sd.y < 0.f) ? 1.f : 0.f);

    return omega * sgn * mk2(0.15915494309189535f, 0.15915494309189535f);
}

// =========== table kernel: batch-invariant index maps, once per call ========
// Round-7 measurement: kernel is VALU-ISSUE-bound (VALUBusy 57%, ~8.5k VALU
// instr/wave), and ~2k of those per thread are Phase 0 + Phase D index math
// that is IDENTICAL across all 512 blocks. Hoist it here (48 blocks, ~2us).
// ptab holds four u16 LDS *byte offsets* per output element; invalid terms
// point at the zero slot (swr[8192] = 0), making Phase D gathers branchless.
__global__ __launch_bounds__(TBLOCK) void build_tables(
    unsigned short* __restrict__ gseg,   // u16[8192] packed (i<<7)|j
    uint2*          __restrict__ ptab)   // [16256] packed 4x u16 byte offsets
{
    const int tid = blockIdx.x * TBLOCK + threadIdx.x;

    if (tid < NSEG_PAD) {
        int i, j;
        if (tid < NSEG) { seed_ij(tid, i, j); }
        else            { i = 124; j = 126; }      // safe pad segment
        gseg[tid] = (unsigned short)((i << 7) | j);
    } else {
        const int k = tid - NSEG_PAD;
        if (k < OUT_PER_B) {
            const int r = (int)(((unsigned)k * 132105u) >> 24);   // k/127 exact
            int c = k - r * 127;
            c += (c >= r);
            const int a  = min(r, c);
            const int bb = max(r, c);

            // segment ids for (i,j) in {a-1,a} x {b-1,b}; s(i,j)=base(i)+j-i-2
            const int am1 = a - 1;
            const int s00 = 125 * am1 - ((am1 * (am1 - 1)) >> 1) + bb - a - 2; // (a-1,b-1)
            const int s10 = s00 + 125 - a;                                     // (a,  b-1)

            const bool v00 = (a >= 1) && (a <= 125) && (bb >= a + 2);
            const bool v01 = (a >= 1) && (a <= 125) && (bb <= 126);
            const bool v10 = (a <= 124) && (bb >= a + 3);
            const bool v11 = (a <= 124) && (bb <= 126) && (bb >= a + 2);

            const unsigned o00 = v00 ? (unsigned)(s00 << 2)       : (unsigned)ZSLOT_OFF;
            const unsigned o01 = v01 ? (unsigned)((s00 + 1) << 2) : (unsigned)ZSLOT_OFF;
            const unsigned o10 = v10 ? (unsigned)(s10 << 2)       : (unsigned)ZSLOT_OFF;
            const unsigned o11 = v11 ? (unsigned)((s10 + 1) << 2) : (unsigned)ZSLOT_OFF;

            ptab[k] = make_uint2(o00 | (o01 << 16), o10 | (o11 << 16));
        }
    }
}

// ===================== main kernel: one block per batch =====================
// Phase 0 deleted (gseg read from global, L2-resident; also removes the
// 16-way-conflicted u16 LDS writes). Phase D: uint2 table entry -> 4
// branchless LDS gathers (byte offsets, zero slot absorbs invalid terms)
// -> ~11 VALU ops/output vs ~55 before.
// LDS: sp4 2K + swr 32.8K ~= 34.8 KB. lb(512,2): measured VGPR=40, no spill.
__global__ __launch_bounds__(BLOCK, 2) void writhe_main(
    const float*          __restrict__ xyz,    // (B, 128, 3)
    const unsigned short* __restrict__ gseg,   // u16[8192]
    const uint2*          __restrict__ ptab,   // [16256]
    float*                __restrict__ out)    // (B, 16256)
{
    __shared__ float4 sp4[NATOMS];
    __shared__ float  swr[NSEG_PAD + 1];       // [8192] = zero slot

    const int b = blockIdx.x;
    const int t = threadIdx.x;

    if (t < 3 * NATOMS) {
        float v = xyz[(size_t)b * (3 * NATOMS) + t];
        int a = t / 3, c = t - 3 * a;
        ((float*)&sp4[a])[c] = v;
    }
    if (t == 0) swr[NSEG_PAD] = 0.0f;          // written once, pre-barrier
    __syncthreads();

    // ---------- Phase A: packed-pair writhe, 2 chains x 4 iterations ----------
    #pragma unroll
    for (int g = 0; g < 4; ++g) {
        const int sA = g * 2048 + t;           // sA..sA+1536 < 8192: unconditional
        v2f w1 = seg_writhe_pair(gseg[sA],        gseg[sA + 512],  sp4);
        v2f w2 = seg_writhe_pair(gseg[sA + 1024], gseg[sA + 1536], sp4);
        swr[sA]        = w1.x;
        swr[sA + 512]  = w1.y;
        swr[sA + 1024] = w2.x;
        swr[sA + 1536] = w2.y;
    }
    __syncthreads();

    // ---------- Phase D: table-driven gather + coalesced store ----------
    // Lane-consecutive k (stride-1 swr offsets across lanes: conflict-free).
    float* ob = out + (size_t)b * OUT_PER_B;
    const char* swb = (const char*)swr;
    for (int k = t; k < OUT_PER_B; k += BLOCK) {
        const uint2 e = ptab[k];
        const float s0 = *(const float*)(swb + (e.x & 0xFFFFu));
        const float s1 = *(const float*)(swb + (e.x >> 16));
        const float s2 = *(const float*)(swb + (e.y & 0xFFFFu));
        const float s3 = *(const float*)(swb + (e.y >> 16));
        __builtin_nontemporal_store(s0 + s1 + s2 + s3, ob + k);
    }
}

// ================== fused fallback (round-6, verified) =====================
__global__ __launch_bounds__(BLOCK, 2) void writhe_fused(
    const float* __restrict__ xyz, float* __restrict__ out)
{
    __shared__ float4 sp4[NATOMS];
    __shared__ float  swr[NSEG_PAD];
    __shared__ unsigned short sidx[NSEG_PAD];
    const int b = blockIdx.x;
    const int t = threadIdx.x;
    if (t < 3 * NATOMS) {
        float v = xyz[(size_t)b * (3 * NATOMS) + t];
        int a = t / 3, c = t - 3 * a;
        ((float*)&sp4[a])[c] = v;
    }
    {
        int s = t * 16;
        if (s < NSEG) {
            int i, j; seed_ij(s, i, j);
            #pragma unroll
            for (int k = 0; k < 16; ++k) {
                if (s < NSEG) sidx[s] = (unsigned short)((i << 7) | j);
                ++s; ++j;
                if (j > 126) { ++i; j = i + 2; }
            }
        }
        if (t < NSEG_PAD - NSEG) sidx[NSEG + t] = (unsigned short)((124 << 7) | 126);
    }
    __syncthreads();
    #pragma unroll
    for (int g = 0; g < 4; ++g) {
        const int sA = g * 2048 + t;
        v2f w1 = seg_writhe_pair(sidx[sA],        sidx[sA + 512],  sp4);
        v2f w2 = seg_writhe_pair(sidx[sA + 1024], sidx[sA + 1536], sp4);
        swr[sA]        = w1.x;
        swr[sA + 512]  = w1.y;
        swr[sA + 1024] = w2.x;
        swr[sA + 1536] = w2.y;
    }
    __syncthreads();
    float* ob = out + (size_t)b * OUT_PER_B;
    for (int k = t; k < OUT_PER_B; k += BLOCK) {
        const int r = (int)(((unsigned)k * 132105u) >> 24);
        int c = k - r * 127;
        c += (c >= r);
        const int a  = min(r, c);
        const int bb = max(r, c);
        const int am1 = a - 1;
        const int s00 = 125 * am1 - ((am1 * (am1 - 1)) >> 1) + bb - a - 2;
        const int s10 = s00 + 125 - a;
        const bool v00 = (a >= 1) && (a <= 125) && (bb >= a + 2);
        const bool v01 = (a >= 1) && (a <= 125) && (bb <= 126);
        const bool v10 = (a <= 124) && (bb >= a + 3);
        const bool v11 = (a <= 124) && (bb <= 126) && (bb >= a + 2);
        const int c00 = min(max(s00,     0), NSEG - 1);
        const int c01 = min(max(s00 + 1, 0), NSEG - 1);
        const int c10 = min(max(s10,     0), NSEG - 1);
        const int c11 = min(max(s10 + 1, 0), NSEG - 1);
        float sum = (v00 ? swr[c00] : 0.0f) + (v01 ? swr[c01] : 0.0f)
                  + (v10 ? swr[c10] : 0.0f) + (v11 ? swr[c11] : 0.0f);
        __builtin_nontemporal_store(sum, ob + k);
    }
}

extern "C" void kernel_launch(void* const* d_in, const int* in_sizes, int n_in,
                              void* d_out, int out_size, void* d_ws, size_t ws_size,
                              hipStream_t stream) {
    const float* xyz = (const float*)d_in[0];
    float*       out = (float*)d_out;

    int B = in_sizes[0] / (NATOMS * 3);   // 512 for the reference shapes

    if (d_ws != nullptr && ws_size >= (size_t)WS_NEED) {
        unsigned short* gseg = (unsigned short*)d_ws;
        uint2*          ptab = (uint2*)((char*)d_ws + SIDX_BYTES);
        const int tgrid = (NSEG_PAD + OUT_PER_B + TBLOCK - 1) / TBLOCK;   // 48
        build_tables<<<tgrid, TBLOCK, 0, stream>>>(gseg, ptab);
        writhe_main<<<B, BLOCK, 0, stream>>>(xyz, gseg, ptab, out);
    } else {
        writhe_fused<<<B, BLOCK, 0, stream>>>(xyz, out);
    }
}